// Round 3
// baseline (56.832 us; speedup 1.0000x reference)
//
#include <hip/hip_runtime.h>

// FoveatedSamplingConv2d — bf16 MFMA implicit GEMM + replicate-padded gather
// out[b,o,h,w] = bias[o] + sum_{c,ky,kx} x[b,c,clip(h+dy),clip(w+dx)] * W[o,c,ky,kx]
// Padded bf16 input bakes the clamps; per-tap address = base + P(lane) + F[tap].

#define HH 256
#define WW 256
#define INC 3
#define OC 64
#define KS 11
#define BB 4
#define KPC 128          // padded taps per input channel
#define NKC 12           // K chunks of 32 (3*128/32)
#define PH 326           // 256 + 2*35
#define PW 512           // padded row stride (pow2)
#define PAD 35

typedef __attribute__((ext_vector_type(4))) float f32x4;
typedef __attribute__((ext_vector_type(8))) short s16x8;
typedef unsigned int u32;
typedef unsigned short u16;

static __device__ __forceinline__ u16 f2bf(float f) {
    u32 u = __builtin_bit_cast(u32, f);
    u32 r = (u + 0x7FFFu + ((u >> 16) & 1u)) >> 16;   // RTNE (finite data)
    return (u16)r;
}

// ---- prep: fp32 x -> replicate-padded bf16 [bc][PH][PW] -----------------
__global__ void prep_pad(const float* __restrict__ x, u16* __restrict__ xp) {
    const int px = threadIdx.x;        // 0..511
    const int py = blockIdx.x;         // 0..325
    const int bc = blockIdx.y;         // 0..11
    const int sx = min(max(px - PAD, 0), WW - 1);
    const int sy = min(max(py - PAD, 0), HH - 1);
    xp[((size_t)bc * PH + py) * PW + px] = f2bf(x[((size_t)bc * HH + sy) * WW + sx]);
}

// ---- prep: W (O,C,11,11) fp32 -> bf16 A-fragment order ------------------
// o = ot*16 + (lane&15) ; k = kc*32 + (lane>>4)*8 + j ; c = k>>7 ; tt = k&127
__global__ void prep_wfrag(const float* __restrict__ w, u16* __restrict__ wf) {
    int i = blockIdx.x * 256 + threadIdx.x;          // 0..24575
    int j    = i & 7;
    int lane = (i >> 3) & 63;
    int ot   = (i >> 9) & 3;
    int kc   = i >> 11;
    int o  = ot * 16 + (lane & 15);
    int k  = kc * 32 + ((lane >> 4) << 3) + j;
    int c  = k >> 7;
    int tt = k & 127;
    float val = 0.f;
    if (tt < 121) {
        int ky = tt / 11, kx = tt % 11;
        val = w[((o * INC + c) * KS + ky) * KS + kx];
    }
    wf[i] = f2bf(val);
}

// ---- main: 256 thr = 4 waves; wave = 16 pixels --------------------------
__global__ void __launch_bounds__(256)
fov_mfma(const u16* __restrict__ xp, const u16* __restrict__ wf,
         const float* __restrict__ bias, float* __restrict__ out) {
    __shared__ u32 offF[NKC * 32];
    const int tid = threadIdx.x;
    for (int t = tid; t < NKC * 32; t += 256) {
        int c = t >> 7, tt = t & 127;
        int dy = 0, dx = 0;
        if (tt < 121) {
            int ky = tt / 11, kx = tt - (tt / 11) * 11;
            int ay = ky - 5, ax = kx - 5;
            int d = max(abs(ay), abs(ax));
            int sc = (d <= 1) ? 1 : (d == 2 ? 3 : (d == 3 ? 5 : 7));
            dy = ay * sc; dx = ax * sc;
        }
        offF[t] = (u32)(((c * PH + PAD + dy) * PW + PAD + dx) * 2);
    }
    __syncthreads();

    const int lane = tid & 63;
    const int wv   = tid >> 6;
    const int h    = (blockIdx.x >> 2) & (HH - 1);
    const int b    = blockIdx.x >> 10;
    const int wpix = (blockIdx.x & 3) * 64 + wv * 16 + (lane & 15);
    const int tgrp = (lane >> 4) << 3;

    const char* xpb = (const char*)(xp + (size_t)b * (INC * PH * PW));
    const u32 Pb = (u32)((h * PW + wpix) * 2);

    f32x4 acc0 = {0,0,0,0}, acc1 = {0,0,0,0}, acc2 = {0,0,0,0}, acc3 = {0,0,0,0};

#pragma unroll
    for (int kc = 0; kc < NKC; ++kc) {
        const uint4* fp = (const uint4*)&offF[kc * 32 + tgrp];
        const uint4 fA = fp[0], fB = fp[1];

        // gather 8 taps; ushort2 halves -> d16/d16_hi merge opportunity
        ushort2 q0, q1, q2, q3;
        q0.x = *(const u16*)(xpb + (Pb + fA.x));
        q0.y = *(const u16*)(xpb + (Pb + fA.y));
        q1.x = *(const u16*)(xpb + (Pb + fA.z));
        q1.y = *(const u16*)(xpb + (Pb + fA.w));
        q2.x = *(const u16*)(xpb + (Pb + fB.x));
        q2.y = *(const u16*)(xpb + (Pb + fB.y));
        q3.x = *(const u16*)(xpb + (Pb + fB.z));
        q3.y = *(const u16*)(xpb + (Pb + fB.w));

        union { u32 u[4]; s16x8 v; } bu;
        bu.u[0] = __builtin_bit_cast(u32, q0);
        bu.u[1] = __builtin_bit_cast(u32, q1);
        bu.u[2] = __builtin_bit_cast(u32, q2);
        bu.u[3] = __builtin_bit_cast(u32, q3);

        const s16x8* wfp = ((const s16x8*)wf) + ((kc << 8) + lane);
        s16x8 a0 = wfp[0], a1 = wfp[64], a2 = wfp[128], a3 = wfp[192];

        acc0 = __builtin_amdgcn_mfma_f32_16x16x32_bf16(a0, bu.v, acc0, 0, 0, 0);
        acc1 = __builtin_amdgcn_mfma_f32_16x16x32_bf16(a1, bu.v, acc1, 0, 0, 0);
        acc2 = __builtin_amdgcn_mfma_f32_16x16x32_bf16(a2, bu.v, acc2, 0, 0, 0);
        acc3 = __builtin_amdgcn_mfma_f32_16x16x32_bf16(a3, bu.v, acc3, 0, 0, 0);
    }

    // D: col = lane&15 = pixel, row = (lane>>4)*4 + r = o within 16-tile
    const int orow = (lane >> 4) << 2;
    float* op = out + (size_t)b * OC * HH * WW + h * WW + wpix;
#pragma unroll
    for (int r = 0; r < 4; ++r) {
        int o0 = orow + r;
        op[(size_t)(o0)      * (HH * WW)] = acc0[r] + bias[o0];
        op[(size_t)(o0 + 16) * (HH * WW)] = acc1[r] + bias[o0 + 16];
        op[(size_t)(o0 + 32) * (HH * WW)] = acc2[r] + bias[o0 + 32];
        op[(size_t)(o0 + 48) * (HH * WW)] = acc3[r] + bias[o0 + 48];
    }
}

// ---------------- fallback (R1 fp32 path, if ws too small) ---------------
__global__ void fovconv_transpose_w(const float* __restrict__ w,
                                    float* __restrict__ wT) {
    int i = blockIdx.x * 256 + threadIdx.x;
    const int N = OC * INC * KS * KS;
    if (i < N) {
        int o  = i / (INC * KS * KS);
        int ct = i % (INC * KS * KS);
        wT[ct * OC + o] = w[i];
    }
}

__global__ void __launch_bounds__(256)
fovconv_main(const float* __restrict__ x, const float* __restrict__ wT,
             const float* __restrict__ bias, float* __restrict__ out) {
    const int wpix = threadIdx.x;
    const int h    = blockIdx.x & (HH - 1);
    const int b    = blockIdx.x >> 8;
    float acc[OC];
#pragma unroll
    for (int o = 0; o < OC; ++o) acc[o] = 0.f;
    const float* xbp = x + (size_t)b * INC * HH * WW;
    for (int k = 0; k < KS; ++k) {
        const int dy = k - 5;
        for (int l = 0; l < KS; ++l) {
            const int dx = l - 5;
            const int d  = max(abs(dy), abs(dx));
            const int scale = (d <= 1) ? 1 : (d == 2 ? 3 : (d == 3 ? 5 : 7));
            const int sy = min(max(h + dy * scale, 0), HH - 1);
            const int sx = min(max(wpix + dx * scale, 0), WW - 1);
            const int base = sy * WW + sx;
            const int t = k * KS + l;
#pragma unroll
            for (int c = 0; c < INC; ++c) {
                const float xv = xbp[c * (HH * WW) + base];
                const float* wp = wT + (c * (KS * KS) + t) * OC;
#pragma unroll
                for (int o = 0; o < OC; ++o)
                    acc[o] = fmaf(xv, wp[o], acc[o]);
            }
        }
    }
    float* op = out + (((size_t)b * OC) * HH + h) * WW + wpix;
#pragma unroll
    for (int o = 0; o < OC; ++o)
        op[(size_t)o * HH * WW] = acc[o] + bias[o];
}

extern "C" void kernel_launch(void* const* d_in, const int* in_sizes, int n_in,
                              void* d_out, int out_size, void* d_ws, size_t ws_size,
                              hipStream_t stream) {
    const float* x    = (const float*)d_in[0];
    const float* wgt  = (const float*)d_in[1];
    const float* bias = (const float*)d_in[2];
    float* out = (float*)d_out;

    const size_t xp_bytes = (size_t)BB * INC * PH * PW * 2;   // 4,005,888
    const size_t wf_bytes = (size_t)NKC * 4 * 64 * 8 * 2;     // 49,152

    if (ws_size >= xp_bytes + wf_bytes) {
        u16* xpad = (u16*)d_ws;
        u16* wf   = (u16*)((char*)d_ws + xp_bytes);
        dim3 pgrid(PH, BB * INC);
        prep_pad<<<pgrid, PW, 0, stream>>>(x, xpad);
        prep_wfrag<<<(NKC * 4 * 64 * 8) / 256, 256, 0, stream>>>(wgt, wf);
        fov_mfma<<<BB * HH * (WW / 64), 256, 0, stream>>>(xpad, wf, bias, out);
    } else {
        float* wT = (float*)d_ws;
        const int NW = OC * INC * KS * KS;
        fovconv_transpose_w<<<(NW + 255) / 256, 256, 0, stream>>>(wgt, wT);
        fovconv_main<<<BB * HH, 256, 0, stream>>>(x, wT, bias, out);
    }
}

// Round 4
// 48.620 us; speedup vs baseline: 1.1689x; 1.1689x over previous
//
#include <hip/hip_runtime.h>

// FoveatedSamplingConv2d — bf16 MFMA implicit GEMM, 4-px-per-lane gathers.
// 4 shifted replicate-padded bf16 copies make every tap gather 8B-aligned:
// copy par = (35+dx)&3, addr = base + F[tap] + (h*PW + wv*64 + 4*(lane&15))*2.
// Each lane owns 4 consecutive pixels -> one dwordx2 per tap feeds 4 MFMA
// tiles; epilogue stores are dense dwordx4 per lane.

#define HH 256
#define WW 256
#define INC 3
#define OC 64
#define KS 11
#define BB 4
#define KPC 128          // padded taps per input channel
#define NKC 12           // K chunks of 32 (3*128/32)
#define PH 326           // 256 + 2*35
#define PW 512           // padded row stride
#define PAD 35
#define NPAR 4           // shifted copies

typedef __attribute__((ext_vector_type(4))) float f32x4;
typedef __attribute__((ext_vector_type(8))) short s16x8;
typedef unsigned int u32;
typedef unsigned short u16;

static __device__ __forceinline__ u16 f2bf(float f) {
    u32 u = __builtin_bit_cast(u32, f);
    u32 r = (u + 0x7FFFu + ((u >> 16) & 1u)) >> 16;   // RTNE (finite data)
    return (u16)r;
}

// ---- prep: 4 shifted replicate-padded bf16 copies [b][par][c][PH][PW] ----
__global__ void prep_pad4(const float* __restrict__ x, u16* __restrict__ xs) {
    const int px = threadIdx.x;        // 0..511
    const int py = blockIdx.x;         // 0..325
    const int z  = blockIdx.y;         // (b*NPAR + par)*INC + c, 0..47
    const int c   = z % INC;
    const int par = (z / INC) & 3;
    const int b   = z / (INC * NPAR);
    const int sx = min(max(px - PAD + par, 0), WW - 1);
    const int sy = min(max(py - PAD, 0), HH - 1);
    xs[((size_t)z * PH + py) * PW + px] =
        f2bf(x[(((size_t)b * INC + c) * HH + sy) * WW + sx]);
}

// ---- prep: W (O,C,11,11) fp32 -> bf16 A-fragment order ------------------
__global__ void prep_wfrag(const float* __restrict__ w, u16* __restrict__ wf) {
    int i = blockIdx.x * 256 + threadIdx.x;          // 0..24575
    int j    = i & 7;
    int lane = (i >> 3) & 63;
    int ot   = (i >> 9) & 3;
    int kc   = i >> 11;
    int o  = ot * 16 + (lane & 15);
    int k  = kc * 32 + ((lane >> 4) << 3) + j;
    int c  = k >> 7;
    int tt = k & 127;
    float val = 0.f;
    if (tt < 121) {
        int ky = tt / 11, kx = tt % 11;
        val = w[((o * INC + c) * KS + ky) * KS + kx];
    }
    wf[i] = f2bf(val);
}

// ---- main: 256 thr = 4 waves; wave = 64 px (4 MFMA tiles), block = row ---
__global__ void __launch_bounds__(256)
fov_mfma4(const u16* __restrict__ xs, const u16* __restrict__ wf,
          const float* __restrict__ bias, float* __restrict__ out) {
    __shared__ u32 offF[NKC * 32];
    const int tid = threadIdx.x;
    for (int t = tid; t < NKC * 32; t += 256) {
        int c = t >> 7, tt = t & 127;
        int dy = 0, dx = 0;
        if (tt < 121) {
            int ky = tt / 11, kx = tt - (tt / 11) * 11;
            int ay = ky - 5, ax = kx - 5;
            int d = max(abs(ay), abs(ax));
            int sc = (d <= 1) ? 1 : (d == 2 ? 3 : (d == 3 ? 5 : 7));
            dy = ay * sc; dx = ax * sc;
        }
        int par = (PAD + dx) & 3;
        offF[t] = (u32)(((((par * INC + c) * PH) + (PAD + dy)) * PW
                         + (PAD + dx - par)) * 2);
    }
    __syncthreads();

    const int lane = tid & 63;
    const int wv   = tid >> 6;
    // bijective XCD swizzle (1024 % 8 == 0): each XCD gets contiguous rows
    const int obid = (blockIdx.x & 7) * 128 + (blockIdx.x >> 3);
    const int b = obid >> 8;
    const int h = obid & 255;
    const int g  = lane & 15;          // pixel group: px = wv*64 + 4g + T
    const int kg = lane >> 4;          // tap group within chunk
    const int tgrp = kg << 3;

    const char* xpb = (const char*)(xs + (size_t)b * (NPAR * INC * PH * PW));
    const u32 pxoff = (u32)((h * PW + wv * 64 + 4 * g) * 2);

    f32x4 acc[4][4];                   // [tile T][o-block]
#pragma unroll
    for (int T = 0; T < 4; ++T)
#pragma unroll
        for (int ob = 0; ob < 4; ++ob) acc[T][ob] = (f32x4){0, 0, 0, 0};

#pragma unroll
    for (int kc = 0; kc < NKC; ++kc) {
        const uint4* fp = (const uint4*)&offF[kc * 32 + tgrp];
        const uint4 fA = fp[0], fB = fp[1];

        // 8 taps x 4 px per lane (dwordx2, 8B-aligned by construction)
        uint2 g0 = *(const uint2*)(xpb + (pxoff + fA.x));
        uint2 g1 = *(const uint2*)(xpb + (pxoff + fA.y));
        uint2 g2 = *(const uint2*)(xpb + (pxoff + fA.z));
        uint2 g3 = *(const uint2*)(xpb + (pxoff + fA.w));
        uint2 g4 = *(const uint2*)(xpb + (pxoff + fB.x));
        uint2 g5 = *(const uint2*)(xpb + (pxoff + fB.y));
        uint2 g6 = *(const uint2*)(xpb + (pxoff + fB.z));
        uint2 g7 = *(const uint2*)(xpb + (pxoff + fB.w));

        const s16x8* wfp = ((const s16x8*)wf) + ((kc << 8) + lane);
        s16x8 a0 = wfp[0], a1 = wfp[64], a2 = wfp[128], a3 = wfp[192];

#pragma unroll
        for (int T = 0; T < 4; ++T) {
            const u32 sel = (T & 1) ? 0x07060302u : 0x05040100u;
            const bool hi = (T >> 1) != 0;
            union { u32 u[4]; s16x8 v; } bu;
            bu.u[0] = __builtin_amdgcn_perm(hi ? g1.y : g1.x, hi ? g0.y : g0.x, sel);
            bu.u[1] = __builtin_amdgcn_perm(hi ? g3.y : g3.x, hi ? g2.y : g2.x, sel);
            bu.u[2] = __builtin_amdgcn_perm(hi ? g5.y : g5.x, hi ? g4.y : g4.x, sel);
            bu.u[3] = __builtin_amdgcn_perm(hi ? g7.y : g7.x, hi ? g6.y : g6.x, sel);

            acc[T][0] = __builtin_amdgcn_mfma_f32_16x16x32_bf16(a0, bu.v, acc[T][0], 0, 0, 0);
            acc[T][1] = __builtin_amdgcn_mfma_f32_16x16x32_bf16(a1, bu.v, acc[T][1], 0, 0, 0);
            acc[T][2] = __builtin_amdgcn_mfma_f32_16x16x32_bf16(a2, bu.v, acc[T][2], 0, 0, 0);
            acc[T][3] = __builtin_amdgcn_mfma_f32_16x16x32_bf16(a3, bu.v, acc[T][3], 0, 0, 0);
        }
    }

    // D: col = lane&15 = pixel-group, row = kg*4 + r = o within 16-block.
    // Lane holds tiles T=0..3 for ITS pixel quad -> dense float4 store.
    const int orow = kg << 2;
    const float4* bp = (const float4*)bias;     // bias[ob*16 + orow .. +3]
#pragma unroll
    for (int ob = 0; ob < 4; ++ob) {
        const float4 bb = bp[ob * 4 + kg];
        const float bv[4] = {bb.x, bb.y, bb.z, bb.w};
#pragma unroll
        for (int r = 0; r < 4; ++r) {
            const int o = ob * 16 + orow + r;
            float4 st;
            st.x = acc[0][ob][r] + bv[r];
            st.y = acc[1][ob][r] + bv[r];
            st.z = acc[2][ob][r] + bv[r];
            st.w = acc[3][ob][r] + bv[r];
            float* op = out + (((size_t)b * OC + o) * HH + h) * WW + wv * 64 + 4 * g;
            *(float4*)op = st;
        }
    }
}

// ================= fallback A (R3 path, 4MB ws) ==========================
__global__ void prep_pad(const float* __restrict__ x, u16* __restrict__ xp) {
    const int px = threadIdx.x;
    const int py = blockIdx.x;
    const int bc = blockIdx.y;
    const int sx = min(max(px - PAD, 0), WW - 1);
    const int sy = min(max(py - PAD, 0), HH - 1);
    xp[((size_t)bc * PH + py) * PW + px] = f2bf(x[((size_t)bc * HH + sy) * WW + sx]);
}

__global__ void __launch_bounds__(256)
fov_mfma(const u16* __restrict__ xp, const u16* __restrict__ wf,
         const float* __restrict__ bias, float* __restrict__ out) {
    __shared__ u32 offF[NKC * 32];
    const int tid = threadIdx.x;
    for (int t = tid; t < NKC * 32; t += 256) {
        int c = t >> 7, tt = t & 127;
        int dy = 0, dx = 0;
        if (tt < 121) {
            int ky = tt / 11, kx = tt - (tt / 11) * 11;
            int ay = ky - 5, ax = kx - 5;
            int d = max(abs(ay), abs(ax));
            int sc = (d <= 1) ? 1 : (d == 2 ? 3 : (d == 3 ? 5 : 7));
            dy = ay * sc; dx = ax * sc;
        }
        offF[t] = (u32)(((c * PH + PAD + dy) * PW + PAD + dx) * 2);
    }
    __syncthreads();

    const int lane = tid & 63;
    const int wv   = tid >> 6;
    const int h    = (blockIdx.x >> 2) & (HH - 1);
    const int b    = blockIdx.x >> 10;
    const int wpix = (blockIdx.x & 3) * 64 + wv * 16 + (lane & 15);
    const int tgrp = (lane >> 4) << 3;

    const char* xpb = (const char*)(xp + (size_t)b * (INC * PH * PW));
    const u32 Pb = (u32)((h * PW + wpix) * 2);

    f32x4 acc0 = {0,0,0,0}, acc1 = {0,0,0,0}, acc2 = {0,0,0,0}, acc3 = {0,0,0,0};

#pragma unroll
    for (int kc = 0; kc < NKC; ++kc) {
        const uint4* fp = (const uint4*)&offF[kc * 32 + tgrp];
        const uint4 fA = fp[0], fB = fp[1];
        ushort2 q0, q1, q2, q3;
        q0.x = *(const u16*)(xpb + (Pb + fA.x));
        q0.y = *(const u16*)(xpb + (Pb + fA.y));
        q1.x = *(const u16*)(xpb + (Pb + fA.z));
        q1.y = *(const u16*)(xpb + (Pb + fA.w));
        q2.x = *(const u16*)(xpb + (Pb + fB.x));
        q2.y = *(const u16*)(xpb + (Pb + fB.y));
        q3.x = *(const u16*)(xpb + (Pb + fB.z));
        q3.y = *(const u16*)(xpb + (Pb + fB.w));
        union { u32 u[4]; s16x8 v; } bu;
        bu.u[0] = __builtin_bit_cast(u32, q0);
        bu.u[1] = __builtin_bit_cast(u32, q1);
        bu.u[2] = __builtin_bit_cast(u32, q2);
        bu.u[3] = __builtin_bit_cast(u32, q3);
        const s16x8* wfp = ((const s16x8*)wf) + ((kc << 8) + lane);
        s16x8 a0 = wfp[0], a1 = wfp[64], a2 = wfp[128], a3 = wfp[192];
        acc0 = __builtin_amdgcn_mfma_f32_16x16x32_bf16(a0, bu.v, acc0, 0, 0, 0);
        acc1 = __builtin_amdgcn_mfma_f32_16x16x32_bf16(a1, bu.v, acc1, 0, 0, 0);
        acc2 = __builtin_amdgcn_mfma_f32_16x16x32_bf16(a2, bu.v, acc2, 0, 0, 0);
        acc3 = __builtin_amdgcn_mfma_f32_16x16x32_bf16(a3, bu.v, acc3, 0, 0, 0);
    }

    const int orow = (lane >> 4) << 2;
    float* op = out + (size_t)b * OC * HH * WW + h * WW + wpix;
#pragma unroll
    for (int r = 0; r < 4; ++r) {
        int o0 = orow + r;
        op[(size_t)(o0)      * (HH * WW)] = acc0[r] + bias[o0];
        op[(size_t)(o0 + 16) * (HH * WW)] = acc1[r] + bias[o0 + 16];
        op[(size_t)(o0 + 32) * (HH * WW)] = acc2[r] + bias[o0 + 32];
        op[(size_t)(o0 + 48) * (HH * WW)] = acc3[r] + bias[o0 + 48];
    }
}

// ================= fallback B (R1 fp32 path) =============================
__global__ void fovconv_transpose_w(const float* __restrict__ w,
                                    float* __restrict__ wT) {
    int i = blockIdx.x * 256 + threadIdx.x;
    const int N = OC * INC * KS * KS;
    if (i < N) {
        int o  = i / (INC * KS * KS);
        int ct = i % (INC * KS * KS);
        wT[ct * OC + o] = w[i];
    }
}

__global__ void __launch_bounds__(256)
fovconv_main(const float* __restrict__ x, const float* __restrict__ wT,
             const float* __restrict__ bias, float* __restrict__ out) {
    const int wpix = threadIdx.x;
    const int h    = blockIdx.x & (HH - 1);
    const int b    = blockIdx.x >> 8;
    float acc[OC];
#pragma unroll
    for (int o = 0; o < OC; ++o) acc[o] = 0.f;
    const float* xbp = x + (size_t)b * INC * HH * WW;
    for (int k = 0; k < KS; ++k) {
        const int dy = k - 5;
        for (int l = 0; l < KS; ++l) {
            const int dx = l - 5;
            const int d  = max(abs(dy), abs(dx));
            const int scale = (d <= 1) ? 1 : (d == 2 ? 3 : (d == 3 ? 5 : 7));
            const int sy = min(max(h + dy * scale, 0), HH - 1);
            const int sx = min(max(wpix + dx * scale, 0), WW - 1);
            const int base = sy * WW + sx;
            const int t = k * KS + l;
#pragma unroll
            for (int c = 0; c < INC; ++c) {
                const float xv = xbp[c * (HH * WW) + base];
                const float* wp = wT + (c * (KS * KS) + t) * OC;
#pragma unroll
                for (int o = 0; o < OC; ++o)
                    acc[o] = fmaf(xv, wp[o], acc[o]);
            }
        }
    }
    float* op = out + (((size_t)b * OC) * HH + h) * WW + wpix;
#pragma unroll
    for (int o = 0; o < OC; ++o)
        op[(size_t)o * HH * WW] = acc[o] + bias[o];
}

extern "C" void kernel_launch(void* const* d_in, const int* in_sizes, int n_in,
                              void* d_out, int out_size, void* d_ws, size_t ws_size,
                              hipStream_t stream) {
    const float* x    = (const float*)d_in[0];
    const float* wgt  = (const float*)d_in[1];
    const float* bias = (const float*)d_in[2];
    float* out = (float*)d_out;

    const size_t xs_bytes = (size_t)BB * NPAR * INC * PH * PW * 2;  // 16,023,552
    const size_t xp_bytes = (size_t)BB * INC * PH * PW * 2;         //  4,005,888
    const size_t wf_bytes = (size_t)NKC * 4 * 64 * 8 * 2;           //     49,152

    if (ws_size >= xs_bytes + wf_bytes) {
        u16* xsb = (u16*)d_ws;
        u16* wf  = (u16*)((char*)d_ws + xs_bytes);
        dim3 pgrid(PH, BB * NPAR * INC);
        prep_pad4<<<pgrid, PW, 0, stream>>>(x, xsb);
        prep_wfrag<<<(NKC * 4 * 64 * 8) / 256, 256, 0, stream>>>(wgt, wf);
        fov_mfma4<<<BB * HH, 256, 0, stream>>>(xsb, wf, bias, out);
    } else if (ws_size >= xp_bytes + wf_bytes) {
        u16* xpad = (u16*)d_ws;
        u16* wf   = (u16*)((char*)d_ws + xp_bytes);
        dim3 pgrid(PH, BB * INC);
        prep_pad<<<pgrid, PW, 0, stream>>>(x, xpad);
        prep_wfrag<<<(NKC * 4 * 64 * 8) / 256, 256, 0, stream>>>(wgt, wf);
        fov_mfma<<<BB * HH * (WW / 64), 256, 0, stream>>>(xpad, wf, bias, out);
    } else {
        float* wT = (float*)d_ws;
        const int NW = OC * INC * KS * KS;
        fovconv_transpose_w<<<(NW + 255) / 256, 256, 0, stream>>>(wgt, wT);
        fovconv_main<<<BB * HH, 256, 0, stream>>>(x, wT, bias, out);
    }
}

// Round 5
// 42.699 us; speedup vs baseline: 1.3310x; 1.1387x over previous
//
#include <hip/hip_runtime.h>

// FoveatedSamplingConv2d — bf16 MFMA implicit GEMM, 4-px-per-lane gathers,
// explicit 2-stage register pipeline over K-chunks + relaxed VGPR budget.
// 4 shifted replicate-padded bf16 copies make every tap gather 8B-aligned.

#define HH 256
#define WW 256
#define INC 3
#define OC 64
#define KS 11
#define BB 4
#define KPC 128          // padded taps per input channel
#define NKC 12           // K chunks of 32 (3*128/32)
#define PH 326           // 256 + 2*35
#define PW 512           // padded row stride
#define PAD 35
#define NPAR 4           // shifted copies

typedef __attribute__((ext_vector_type(4))) float f32x4;
typedef __attribute__((ext_vector_type(8))) short s16x8;
typedef unsigned int u32;
typedef unsigned short u16;

static __device__ __forceinline__ u16 f2bf(float f) {
    u32 u = __builtin_bit_cast(u32, f);
    u32 r = (u + 0x7FFFu + ((u >> 16) & 1u)) >> 16;   // RTNE (finite data)
    return (u16)r;
}

// ---- fused prep: blocks [0,96) -> W fragments; [96,7920) -> pad copies ---
// wf layout: flat idx ((kc*4 + ot)*64 + lane)*8 + j (bf16 A-fragments)
// xs layout: [z=(b*4+par)*3+c][PH][PW] bf16, replicate-padded, shift par
__global__ void __launch_bounds__(256)
prep_fused(const float* __restrict__ x, const float* __restrict__ w,
           u16* __restrict__ xs, u16* __restrict__ wf) {
    const int tid = threadIdx.x;
    if (blockIdx.x < 96) {
        int i = blockIdx.x * 256 + tid;              // 0..24575
        int j    = i & 7;
        int lane = (i >> 3) & 63;
        int ot   = (i >> 9) & 3;
        int kc   = i >> 11;
        int o  = ot * 16 + (lane & 15);
        int k  = kc * 32 + ((lane >> 4) << 3) + j;
        int c  = k >> 7;
        int tt = k & 127;
        float val = 0.f;
        if (tt < 121) {
            int ky = tt / 11, kx = tt % 11;
            val = w[((o * INC + c) * KS + ky) * KS + kx];
        }
        wf[i] = f2bf(val);
    } else {
        const int pb   = blockIdx.x - 96;            // 0..7823
        const int row  = pb * 2 + (tid >> 7);        // 0..15647
        const int py   = row % PH;
        const int z    = row / PH;                   // 0..47
        const int c    = z % INC;
        const int par  = (z / INC) & 3;
        const int b    = z / (INC * NPAR);
        const int px0  = (tid & 127) * 4;
        const int sy   = min(max(py - PAD, 0), HH - 1);
        const float* src = x + (((size_t)b * INC + c) * HH + sy) * WW;
        ushort4 o4;
        {
            int s0 = min(max(px0 + 0 - PAD + par, 0), WW - 1);
            int s1 = min(max(px0 + 1 - PAD + par, 0), WW - 1);
            int s2 = min(max(px0 + 2 - PAD + par, 0), WW - 1);
            int s3 = min(max(px0 + 3 - PAD + par, 0), WW - 1);
            o4.x = f2bf(src[s0]); o4.y = f2bf(src[s1]);
            o4.z = f2bf(src[s2]); o4.w = f2bf(src[s3]);
        }
        *(ushort4*)&xs[((size_t)z * PH + py) * PW + px0] = o4;
    }
}

// ---- main: 4 waves; wave = 64 px (4 MFMA tiles); 2-stage kc pipeline -----
__global__ void __launch_bounds__(256, 3)
fov_mfma5(const u16* __restrict__ xs, const u16* __restrict__ wf,
          const float* __restrict__ bias, float* __restrict__ out) {
    __shared__ u32 offF[NKC * 32];
    const int tid = threadIdx.x;
    for (int t = tid; t < NKC * 32; t += 256) {
        int c = t >> 7, tt = t & 127;
        int dy = 0, dx = 0;
        if (tt < 121) {
            int ky = tt / 11, kx = tt - (tt / 11) * 11;
            int ay = ky - 5, ax = kx - 5;
            int d = max(abs(ay), abs(ax));
            int sc = (d <= 1) ? 1 : (d == 2 ? 3 : (d == 3 ? 5 : 7));
            dy = ay * sc; dx = ax * sc;
        }
        int par = (PAD + dx) & 3;
        offF[t] = (u32)(((((par * INC + c) * PH) + (PAD + dy)) * PW
                         + (PAD + dx - par)) * 2);
    }
    __syncthreads();

    const int lane = tid & 63;
    const int wv   = tid >> 6;
    // bijective XCD swizzle (1024 % 8 == 0): contiguous rows per XCD
    const int obid = (blockIdx.x & 7) * 128 + (blockIdx.x >> 3);
    const int b = obid >> 8;
    const int h = obid & 255;
    const int g16 = lane & 15;         // pixel group: px = wv*64 + 4*g16 + T
    const int kg  = lane >> 4;         // tap group within chunk

    const char* xpb = (const char*)(xs + (size_t)b * (NPAR * INC * PH * PW));
    const u32 pxoff = (u32)((h * PW + wv * 64 + 4 * g16) * 2);
    const s16x8* wbase = (const s16x8*)wf;

    f32x4 acc[4][4];                   // [tile T][o-block]
#pragma unroll
    for (int T = 0; T < 4; ++T)
#pragma unroll
        for (int ob = 0; ob < 4; ++ob) acc[T][ob] = (f32x4){0, 0, 0, 0};

    uint2 G[2][8];                     // gather double-buffer
    s16x8 A[2][4];                     // weight double-buffer

    // prologue: stage kc = 0
    {
        const uint4* fp = (const uint4*)&offF[kg * 8];
        const uint4 fA = fp[0], fB = fp[1];
        G[0][0] = *(const uint2*)(xpb + (pxoff + fA.x));
        G[0][1] = *(const uint2*)(xpb + (pxoff + fA.y));
        G[0][2] = *(const uint2*)(xpb + (pxoff + fA.z));
        G[0][3] = *(const uint2*)(xpb + (pxoff + fA.w));
        G[0][4] = *(const uint2*)(xpb + (pxoff + fB.x));
        G[0][5] = *(const uint2*)(xpb + (pxoff + fB.y));
        G[0][6] = *(const uint2*)(xpb + (pxoff + fB.z));
        G[0][7] = *(const uint2*)(xpb + (pxoff + fB.w));
        const s16x8* wp = wbase + lane;
        A[0][0] = wp[0]; A[0][1] = wp[64]; A[0][2] = wp[128]; A[0][3] = wp[192];
    }

#pragma unroll
    for (int kc = 0; kc < NKC; ++kc) {
        const int cur = kc & 1;
        const int nxt = cur ^ 1;
        if (kc + 1 < NKC) {            // prefetch kc+1 while computing kc
            const uint4* fp = (const uint4*)&offF[(kc + 1) * 32 + kg * 8];
            const uint4 fA = fp[0], fB = fp[1];
            G[nxt][0] = *(const uint2*)(xpb + (pxoff + fA.x));
            G[nxt][1] = *(const uint2*)(xpb + (pxoff + fA.y));
            G[nxt][2] = *(const uint2*)(xpb + (pxoff + fA.z));
            G[nxt][3] = *(const uint2*)(xpb + (pxoff + fA.w));
            G[nxt][4] = *(const uint2*)(xpb + (pxoff + fB.x));
            G[nxt][5] = *(const uint2*)(xpb + (pxoff + fB.y));
            G[nxt][6] = *(const uint2*)(xpb + (pxoff + fB.z));
            G[nxt][7] = *(const uint2*)(xpb + (pxoff + fB.w));
            const s16x8* wp = wbase + (((kc + 1) << 8) + lane);
            A[nxt][0] = wp[0];   A[nxt][1] = wp[64];
            A[nxt][2] = wp[128]; A[nxt][3] = wp[192];
        }
#pragma unroll
        for (int T = 0; T < 4; ++T) {
            const u32 sel = (T & 1) ? 0x07060302u : 0x05040100u;
            const bool hi = (T >> 1) != 0;
            union { u32 u[4]; s16x8 v; } bu;
            bu.u[0] = __builtin_amdgcn_perm(hi ? G[cur][1].y : G[cur][1].x,
                                            hi ? G[cur][0].y : G[cur][0].x, sel);
            bu.u[1] = __builtin_amdgcn_perm(hi ? G[cur][3].y : G[cur][3].x,
                                            hi ? G[cur][2].y : G[cur][2].x, sel);
            bu.u[2] = __builtin_amdgcn_perm(hi ? G[cur][5].y : G[cur][5].x,
                                            hi ? G[cur][4].y : G[cur][4].x, sel);
            bu.u[3] = __builtin_amdgcn_perm(hi ? G[cur][7].y : G[cur][7].x,
                                            hi ? G[cur][6].y : G[cur][6].x, sel);

            acc[T][0] = __builtin_amdgcn_mfma_f32_16x16x32_bf16(A[cur][0], bu.v, acc[T][0], 0, 0, 0);
            acc[T][1] = __builtin_amdgcn_mfma_f32_16x16x32_bf16(A[cur][1], bu.v, acc[T][1], 0, 0, 0);
            acc[T][2] = __builtin_amdgcn_mfma_f32_16x16x32_bf16(A[cur][2], bu.v, acc[T][2], 0, 0, 0);
            acc[T][3] = __builtin_amdgcn_mfma_f32_16x16x32_bf16(A[cur][3], bu.v, acc[T][3], 0, 0, 0);
        }
    }

    // D: col = lane&15 = pixel-group; row = kg*4 + r = o within 16-block.
    const int orow = kg << 2;
    const float4* bp = (const float4*)bias;
#pragma unroll
    for (int ob = 0; ob < 4; ++ob) {
        const float4 bb = bp[ob * 4 + kg];
        const float bv[4] = {bb.x, bb.y, bb.z, bb.w};
#pragma unroll
        for (int r = 0; r < 4; ++r) {
            const int o = ob * 16 + orow + r;
            float4 st;
            st.x = acc[0][ob][r] + bv[r];
            st.y = acc[1][ob][r] + bv[r];
            st.z = acc[2][ob][r] + bv[r];
            st.w = acc[3][ob][r] + bv[r];
            float* op = out + (((size_t)b * OC + o) * HH + h) * WW + wv * 64 + 4 * g16;
            *(float4*)op = st;
        }
    }
}

// ================= fallback (R1 fp32 path, tiny ws) ======================
__global__ void fovconv_transpose_w(const float* __restrict__ w,
                                    float* __restrict__ wT) {
    int i = blockIdx.x * 256 + threadIdx.x;
    const int N = OC * INC * KS * KS;
    if (i < N) {
        int o  = i / (INC * KS * KS);
        int ct = i % (INC * KS * KS);
        wT[ct * OC + o] = w[i];
    }
}

__global__ void __launch_bounds__(256)
fovconv_main(const float* __restrict__ x, const float* __restrict__ wT,
             const float* __restrict__ bias, float* __restrict__ out) {
    const int wpix = threadIdx.x;
    const int h    = blockIdx.x & (HH - 1);
    const int b    = blockIdx.x >> 8;
    float acc[OC];
#pragma unroll
    for (int o = 0; o < OC; ++o) acc[o] = 0.f;
    const float* xbp = x + (size_t)b * INC * HH * WW;
    for (int k = 0; k < KS; ++k) {
        const int dy = k - 5;
        for (int l = 0; l < KS; ++l) {
            const int dx = l - 5;
            const int d  = max(abs(dy), abs(dx));
            const int scale = (d <= 1) ? 1 : (d == 2 ? 3 : (d == 3 ? 5 : 7));
            const int sy = min(max(h + dy * scale, 0), HH - 1);
            const int sx = min(max(wpix + dx * scale, 0), WW - 1);
            const int base = sy * WW + sx;
            const int t = k * KS + l;
#pragma unroll
            for (int c = 0; c < INC; ++c) {
                const float xv = xbp[c * (HH * WW) + base];
                const float* wp = wT + (c * (KS * KS) + t) * OC;
#pragma unroll
                for (int o = 0; o < OC; ++o)
                    acc[o] = fmaf(xv, wp[o], acc[o]);
            }
        }
    }
    float* op = out + (((size_t)b * OC) * HH + h) * WW + wpix;
#pragma unroll
    for (int o = 0; o < OC; ++o)
        op[(size_t)o * HH * WW] = acc[o] + bias[o];
}

extern "C" void kernel_launch(void* const* d_in, const int* in_sizes, int n_in,
                              void* d_out, int out_size, void* d_ws, size_t ws_size,
                              hipStream_t stream) {
    const float* x    = (const float*)d_in[0];
    const float* wgt  = (const float*)d_in[1];
    const float* bias = (const float*)d_in[2];
    float* out = (float*)d_out;

    const size_t xs_bytes = (size_t)BB * NPAR * INC * PH * PW * 2;  // 16,023,552
    const size_t wf_bytes = (size_t)NKC * 4 * 64 * 8 * 2;           //     49,152

    if (ws_size >= xs_bytes + wf_bytes) {
        u16* xsb = (u16*)d_ws;
        u16* wf  = (u16*)((char*)d_ws + xs_bytes);
        // 96 wfrag blocks + 7824 pad blocks (2 padded rows per block)
        prep_fused<<<96 + (PH * BB * NPAR * INC) / 2, 256, 0, stream>>>(x, wgt, xsb, wf);
        fov_mfma5<<<BB * HH, 256, 0, stream>>>(xsb, wf, bias, out);
    } else {
        float* wT = (float*)d_ws;
        const int NW = OC * INC * KS * KS;
        fovconv_transpose_w<<<(NW + 255) / 256, 256, 0, stream>>>(wgt, wT);
        fovconv_main<<<BB * HH, 256, 0, stream>>>(x, wT, bias, out);
    }
}